// Round 4
// baseline (109.425 us; speedup 1.0000x reference)
//
#include <hip/hip_runtime.h>

// Causal linear attention (ELU+1), chunked bf16-MFMA, TWO plain launches.
// R12 = R10 with k_scan ELIMINATED (R11 post-mortem: intra-kernel edits are
// all neutral -> tail is per-launch overhead; remove a dispatch entirely):
//  k1    (NC,B,2): R10 form (128 blocks; R11's quadrant split doubled HBM
//         reads for nothing). Coalesced reads + swizzled LDS transpose ->
//         per-chunk S_c^T (SB) + per-chunk ksum; dumps phiK bf16 (KB) and
//         swizzled V^T bf16 (VT).
//  k_out (NC,B,4): each block builds its OWN exclusive prefix by summing
//         SB[c'<c] (<=124 coalesced uint4 L3 loads/thread, f32 accum) and
//         Ksum[c'<c] (doZ waves) -- bit-identical to the old k_scan
//         (same f32 addend order, single f2bf rounding). Staging is bf16
//         uint4 copies (KB/VT); phiQ register frags reused GEMM2+GEMM4;
//         z fully in MFMA (ones-B rowsum + kprev frags).
// Swizzle: elem (l, row) stored at col ((l>>3 + row>>2)&15)*8 + (l&7);
// read frag (row, kq) at ((kq + row>>2)&15)*8  (verified in R7's k_fused).
// Harness floor ~46us (256MB ws poison fill + input restore); cooperative
// launch adds ~30us replay overhead (R7) -- avoided.

#define EPS 1e-6f

constexpr int Bc = 2;
constexpr int L  = 4096;
constexpr int D  = 128;
constexpr int C  = 128;
constexpr int NC = L / C;   // 32
constexpr int P  = 136;     // LDS row pitch (bf16), rows 16B-aligned

typedef short sh8 __attribute__((ext_vector_type(8)));
typedef float f4  __attribute__((ext_vector_type(4)));

__device__ __forceinline__ float phi(float x) {
    return x > 0.0f ? x + 1.0f : __expf(x);
}
__device__ __forceinline__ unsigned short f2bf(float f) {
    unsigned u = __float_as_uint(f);
    return (unsigned short)((u + 0x7FFFu + ((u >> 16) & 1u)) >> 16);  // RNE
}
__device__ __forceinline__ float bflo(unsigned u) {   // low bf16 of a u32
    return __uint_as_float(u << 16);
}
__device__ __forceinline__ float bfhi(unsigned u) {   // high bf16 of a u32
    return __uint_as_float(u & 0xFFFF0000u);
}
__device__ __forceinline__ unsigned packbf(float a, float b) {
    return (unsigned)f2bf(a) | ((unsigned)f2bf(b) << 16);
}
__device__ __forceinline__ sh8 splat1() {
    sh8 s;
#pragma unroll
    for (int j = 0; j < 8; ++j) s[j] = (short)0x3F80;
    return s;
}

// ---------------------------------------------------------------------------
// k1 (NC,B,2), 512 thr: S_c^T[v][i] = sum_l V[l][v] phiK[l][i] + ksum.
// vs = v half.  All global reads coalesced; transposes in LDS via swizzle.
// Extra outputs: KB = phiK bf16 row-major (vs==0 writes, packed from regs);
//                VT = swizzled V^T bf16 image (each block dumps its 64 rows).
// ---------------------------------------------------------------------------
__global__ __launch_bounds__(512) void k1(
    const float* __restrict__ K, const float* __restrict__ V,
    unsigned short* __restrict__ SB, float* __restrict__ Ksum,
    unsigned short* __restrict__ KB, unsigned short* __restrict__ VT) {
    const int c = blockIdx.x, b = blockIdx.y, vs = blockIdx.z;
    const int tid = threadIdx.x;
    __shared__ __align__(16) unsigned short sVT[64 * P];   // V^T slice [vr][l]
    __shared__ __align__(16) unsigned short sKT[128 * P];  // phiK^T [i][l]
    const size_t base = ((size_t)b * L + (size_t)c * C) * D;

    // V slice: 128 rows x 64 cols f32 = 2048 float4, coalesced
    for (int k = 0; k < 4; ++k) {
        int fi = tid + 512 * k;
        int l = fi >> 4, c4 = fi & 15;      // c4: 16 float4 per row-slice
        float4 vd = *(const float4*)(V + base + (size_t)l * D + vs * 64 + c4 * 4);
        int blk = (((l >> 3) + c4) & 15) * 8 + (l & 7);   // (c4*4+s)>>2 == c4
        sVT[(c4 * 4 + 0) * P + blk] = f2bf(vd.x);
        sVT[(c4 * 4 + 1) * P + blk] = f2bf(vd.y);
        sVT[(c4 * 4 + 2) * P + blk] = f2bf(vd.z);
        sVT[(c4 * 4 + 3) * P + blk] = f2bf(vd.w);
    }
    // K chunk: 128x128 f32 = 4096 float4, coalesced, phi applied.
    // vs==0 also streams the packed bf16 rows out to KB (coalesced uint2).
    for (int k = 0; k < 8; ++k) {
        int fi = tid + 512 * k;
        int l = fi >> 5, i4 = fi & 31;
        float4 kd = *(const float4*)(K + base + (size_t)l * D + i4 * 4);
        int blk = (((l >> 3) + i4) & 15) * 8 + (l & 7);
        unsigned short h0 = f2bf(phi(kd.x)), h1 = f2bf(phi(kd.y));
        unsigned short h2 = f2bf(phi(kd.z)), h3 = f2bf(phi(kd.w));
        sKT[(i4 * 4 + 0) * P + blk] = h0;
        sKT[(i4 * 4 + 1) * P + blk] = h1;
        sKT[(i4 * 4 + 2) * P + blk] = h2;
        sKT[(i4 * 4 + 3) * P + blk] = h3;
        if (vs == 0) {
            uint2 pk;
            pk.x = (unsigned)h0 | ((unsigned)h1 << 16);
            pk.y = (unsigned)h2 | ((unsigned)h3 << 16);
            *(uint2*)(KB + base + (size_t)l * D + i4 * 4) = pk;
        }
    }
    __syncthreads();

    // dump swizzled V^T image (64 rows x 128 entries, compact pitch 128).
    // Straight uint4 copy; global stores fly under the MFMA loop below.
    {
        const size_t vtb = (size_t)(b * NC + c) * D * 128 + (size_t)vs * 64 * 128;
        for (int k = 0; k < 2; ++k) {
            int idx = tid + 512 * k;
            int vr = idx >> 4, c8 = idx & 15;
            *(uint4*)(VT + vtb + vr * 128 + c8 * 8) =
                *(const uint4*)(sVT + vr * P + c8 * 8);
        }
    }

    const int w = tid >> 6, lane = tid & 63;
    const int r = lane & 15, q = lane >> 4;
    const int rbase = (w & 3) * 16;        // v rows within 64
    const int cbase = (w >> 2) * 64;       // i cols: w<4 -> 0, w>=4 -> 64
    const bool doK = ((w & 3) == 0);       // waves 0 (i<64) and 4 (i>=64)
    const sh8 ones = splat1();

    f4 acc[4], kz[4];
#pragma unroll
    for (int f = 0; f < 4; ++f) { acc[f] = {0.f,0.f,0.f,0.f}; kz[f] = {0.f,0.f,0.f,0.f}; }
#pragma unroll
    for (int ks = 0; ks < 4; ++ks) {
        int kq = ks * 4 + q;
        int vr = rbase + r;
        sh8 a = *(const sh8*)(sVT + vr * P + ((kq + (vr >> 2)) & 15) * 8);
#pragma unroll
        for (int f = 0; f < 4; ++f) {
            int ir = cbase + f * 16 + r;
            sh8 bk = *(const sh8*)(sKT + ir * P + ((kq + (ir >> 2)) & 15) * 8);
            acc[f] = __builtin_amdgcn_mfma_f32_16x16x32_bf16(a, bk, acc[f], 0, 0, 0);
            if (doK) kz[f] = __builtin_amdgcn_mfma_f32_16x16x32_bf16(ones, bk, kz[f], 0, 0, 0);
        }
    }
    unsigned short* out = SB + ((size_t)(b * NC + c)) * D * D;
#pragma unroll
    for (int f = 0; f < 4; ++f) {
        int i = cbase + f * 16 + r;
#pragma unroll
        for (int e = 0; e < 4; ++e) {
            int v = vs * 64 + rbase + q * 4 + e;
            out[(size_t)v * D + i] = f2bf(acc[f][e]);
        }
    }
    if (doK && q == 0 && vs == 0) {        // colsum rows identical; row 0
#pragma unroll
        for (int f = 0; f < 4; ++f)
            Ksum[((size_t)(b * NC + c)) * D + cbase + f * 16 + r] = kz[f][0];
    }
}

// ---------------------------------------------------------------------------
// k_out (NC,B,4), rows split 4x32, 512 thr (8 waves: rbase=(w&1)*16,
// col quarter cq=w>>1).  Staging is straight bf16 uint4 copies (KB/VT);
// exclusive prefix built in-block: sacc = sum_{c'<c} SB[c'] (f32, ascending
// -> bit-identical to old k_scan), packed to bf16 into sK after S1;
// doZ waves build kzacc = sum_{c'<c} Ksum[c'] the same way.
// phiQ in register frags (reused by GEMM2+GEMM4); MFMA B-frags from LDS.
// LDS = sK + sVT + sAm + sZ = 78.5KB.  z fully in MFMA.
// ---------------------------------------------------------------------------
__global__ __launch_bounds__(512) void k_out(
    const float* __restrict__ Q, const unsigned short* __restrict__ KB,
    const unsigned short* __restrict__ VT, const unsigned short* __restrict__ SB,
    const float* __restrict__ Ksum, float* __restrict__ Out) {
    const int c = blockIdx.x, b = blockIdx.y, rs = blockIdx.z;
    const int tid = threadIdx.x;
    __shared__ __align__(16) unsigned short sK[128 * P];   // phiK rows -> S^T
    __shared__ __align__(16) unsigned short sVT[128 * P];  // V^T swizzled
    __shared__ __align__(16) unsigned short sAm[32 * P];   // masked A
    __shared__ float sZ[32];
    const size_t obase = ((size_t)b * L + (size_t)c * C) * D;  // f32 Q / Out, KB elems
    const size_t vtb   = (size_t)(b * NC + c) * (size_t)D * 128;
    const int SD = D * D;

    // stage sK <- phiK bf16 rows (2048 uint4, coalesced)
    for (int k = 0; k < 4; ++k) {
        int fi = tid + 512 * k;
        int row = fi >> 4, c8 = fi & 15;
        *(uint4*)(sK + row * P + c8 * 8) =
            *(const uint4*)(KB + obase + (size_t)row * D + c8 * 8);
    }
    // stage sVT <- swizzled V^T image (2048 uint4, coalesced)
    for (int k = 0; k < 4; ++k) {
        int fi = tid + 512 * k;
        int vr = fi >> 4, c8 = fi & 15;
        *(uint4*)(sVT + vr * P + c8 * 8) =
            *(const uint4*)(VT + vtb + (size_t)vr * 128 + c8 * 8);
    }

    const int w = tid >> 6, lane = tid & 63;
    const int r = lane & 15, q = lane >> 4;
    const int rbase = (w & 1) * 16;
    const int cq = w >> 1, cbase = cq * 32;
    const bool doZ = (cq == 3);            // rows covered by w=6 (rbase 0), w=7 (16)

    // phiQ frags in registers (row = rs*32 + rbase + r, k = ks*32 + q*8 .. +7)
    sh8 qf[4];
    {
        const float* qrow = Q + obase + (size_t)(rs * 32 + rbase + r) * D;
#pragma unroll
        for (int ks = 0; ks < 4; ++ks) {
            float4 a0 = *(const float4*)(qrow + ks * 32 + q * 8);
            float4 a1 = *(const float4*)(qrow + ks * 32 + q * 8 + 4);
            sh8 t;
            t[0] = (short)f2bf(phi(a0.x)); t[1] = (short)f2bf(phi(a0.y));
            t[2] = (short)f2bf(phi(a0.z)); t[3] = (short)f2bf(phi(a0.w));
            t[4] = (short)f2bf(phi(a1.x)); t[5] = (short)f2bf(phi(a1.y));
            t[6] = (short)f2bf(phi(a1.z)); t[7] = (short)f2bf(phi(a1.w));
            qf[ks] = t;
        }
    }

    // ---- in-block exclusive prefix: sacc = sum_{c'<c} SB[c'] (f32) ----
    // Thread owns 4 uint4-slices (same slots it will ds_write to sK).
    // Coalesced 16B/lane streams, L2/L3-hot; f32 accum in ascending c'
    // order == old k_scan exactly.
    float sacc[32];
#pragma unroll
    for (int j = 0; j < 32; ++j) sacc[j] = 0.f;
#pragma unroll 2
    for (int cp = 0; cp < c; ++cp) {
        const uint4* sg = (const uint4*)(SB + (size_t)(b * NC + cp) * SD);
#pragma unroll
        for (int k = 0; k < 4; ++k) {
            uint4 vv = sg[tid + 512 * k];
            sacc[k * 8 + 0] += bflo(vv.x); sacc[k * 8 + 1] += bfhi(vv.x);
            sacc[k * 8 + 2] += bflo(vv.y); sacc[k * 8 + 3] += bfhi(vv.y);
            sacc[k * 8 + 4] += bflo(vv.z); sacc[k * 8 + 5] += bfhi(vv.z);
            sacc[k * 8 + 6] += bflo(vv.w); sacc[k * 8 + 7] += bfhi(vv.w);
        }
    }

    // kprev frags for GEMM4 z: kzacc = sum_{c'<c} Ksum[c'] (doZ waves only)
    sh8 bzk[4];
    if (doZ) {
        float kzacc[32];
#pragma unroll
        for (int j = 0; j < 32; ++j) kzacc[j] = 0.f;
        for (int cp = 0; cp < c; ++cp) {
            const float* kp = Ksum + (size_t)(b * NC + cp) * D;
#pragma unroll
            for (int ks = 0; ks < 4; ++ks) {
                float4 f0 = *(const float4*)(kp + ks * 32 + q * 8);
                float4 f1 = *(const float4*)(kp + ks * 32 + q * 8 + 4);
                kzacc[ks * 8 + 0] += f0.x; kzacc[ks * 8 + 1] += f0.y;
                kzacc[ks * 8 + 2] += f0.z; kzacc[ks * 8 + 3] += f0.w;
                kzacc[ks * 8 + 4] += f1.x; kzacc[ks * 8 + 5] += f1.y;
                kzacc[ks * 8 + 6] += f1.z; kzacc[ks * 8 + 7] += f1.w;
            }
        }
#pragma unroll
        for (int ks = 0; ks < 4; ++ks) {
            sh8 t;
#pragma unroll
            for (int j = 0; j < 8; ++j) t[j] = (short)f2bf(kzacc[ks * 8 + j]);
            bzk[ks] = t;
        }
    }
    __syncthreads();                       // S0: sK, sVT staged

    // ---- GEMM2: A = phiQ phiK^T (B-frags from sK rows) ----
    f4 a2[2];
#pragma unroll
    for (int f = 0; f < 2; ++f) a2[f] = {0.f,0.f,0.f,0.f};
#pragma unroll
    for (int ks = 0; ks < 4; ++ks) {
#pragma unroll
        for (int f = 0; f < 2; ++f) {
            sh8 bb = *(const sh8*)(sK + (cbase + f * 16 + r) * P + ks * 32 + q * 8);
            a2[f] = __builtin_amdgcn_mfma_f32_16x16x32_bf16(qf[ks], bb, a2[f], 0, 0, 0);
        }
    }
#pragma unroll
    for (int f = 0; f < 2; ++f) {          // causal mask -> sAm bf16
        int j = cbase + f * 16 + r;
#pragma unroll
        for (int e = 0; e < 4; ++e) {
            int lr = rbase + q * 4 + e;
            sAm[lr * P + j] = f2bf((j <= rs * 32 + lr) ? a2[f][e] : 0.f);
        }
    }
    __syncthreads();                       // S1: sAm ready, sK GEMM2 reads done

    // restage sK <- S_prev^T (pack sacc -> bf16 ds_writes; same slots as
    // the old SB-restage, layout unchanged)
#pragma unroll
    for (int k = 0; k < 4; ++k) {
        int f2 = tid + 512 * k;
        uint4 wv;
        wv.x = packbf(sacc[k * 8 + 0], sacc[k * 8 + 1]);
        wv.y = packbf(sacc[k * 8 + 2], sacc[k * 8 + 3]);
        wv.z = packbf(sacc[k * 8 + 4], sacc[k * 8 + 5]);
        wv.w = packbf(sacc[k * 8 + 6], sacc[k * 8 + 7]);
        *(uint4*)(sK + (f2 >> 4) * P + (f2 & 15) * 8) = wv;
    }

    // ---- GEMM3: acc = Am @ V (+ rowsum z via ones-B) ----
    f4 acc[2], zacc = {0.f,0.f,0.f,0.f};
#pragma unroll
    for (int f = 0; f < 2; ++f) acc[f] = {0.f,0.f,0.f,0.f};
    const sh8 ones = splat1();
#pragma unroll
    for (int ks = 0; ks < 4; ++ks) {
        int kq = ks * 4 + q;
        sh8 a = *(const sh8*)(sAm + (rbase + r) * P + ks * 32 + q * 8);
#pragma unroll
        for (int f = 0; f < 2; ++f) {
            int vr = cbase + f * 16 + r;
            sh8 bv = *(const sh8*)(sVT + vr * P + ((kq + (vr >> 2)) & 15) * 8);
            acc[f] = __builtin_amdgcn_mfma_f32_16x16x32_bf16(a, bv, acc[f], 0, 0, 0);
        }
        if (doZ) zacc = __builtin_amdgcn_mfma_f32_16x16x32_bf16(a, ones, zacc, 0, 0, 0);
    }
    __syncthreads();                       // S2: sK = S_prev^T ready

    // ---- GEMM4: acc += phiQ @ S_prev (+ kprev z) ----
#pragma unroll
    for (int ks = 0; ks < 4; ++ks) {
#pragma unroll
        for (int f = 0; f < 2; ++f) {
            sh8 bs = *(const sh8*)(sK + (cbase + f * 16 + r) * P + ks * 32 + q * 8);
            acc[f] = __builtin_amdgcn_mfma_f32_16x16x32_bf16(qf[ks], bs, acc[f], 0, 0, 0);
        }
        if (doZ) zacc = __builtin_amdgcn_mfma_f32_16x16x32_bf16(qf[ks], bzk[ks], zacc, 0, 0, 0);
    }
    if (doZ && r == 0) {
#pragma unroll
        for (int e = 0; e < 4; ++e) sZ[rbase + q * 4 + e] = zacc[e] + EPS;
    }
    __syncthreads();                       // S3: sZ ready

    // ---- normalize + store ----
#pragma unroll
    for (int f = 0; f < 2; ++f) {
        int v = cbase + f * 16 + r;
#pragma unroll
        for (int e = 0; e < 4; ++e) {
            int lr = rbase + q * 4 + e;
            Out[obase + (size_t)(rs * 32 + lr) * D + v] = acc[f][e] / sZ[lr];
        }
    }
}

extern "C" void kernel_launch(void* const* d_in, const int* in_sizes, int n_in,
                              void* d_out, int out_size, void* d_ws, size_t ws_size,
                              hipStream_t stream) {
    const float* Q = (const float*)d_in[0];
    const float* K = (const float*)d_in[1];
    const float* V = (const float*)d_in[2];
    float* Out = (float*)d_out;
    const size_t SB_BYTES = (size_t)Bc * NC * D * D * 2;   // 2 MB
    unsigned short* SBw = (unsigned short*)d_ws;                         // 2 MB
    unsigned short* KBw = (unsigned short*)((char*)d_ws + SB_BYTES);     // 2 MB
    unsigned short* VTw = (unsigned short*)((char*)d_ws + 2 * SB_BYTES); // 2 MB
    float* Ksum = (float*)((char*)d_ws + 3 * SB_BYTES);                  // 32 KB

    k1<<<dim3(NC, Bc, 2), 512, 0, stream>>>(K, V, SBw, Ksum, KBw, VTw);
    k_out<<<dim3(NC, Bc, 4), 512, 0, stream>>>(Q, KBw, VTw, SBw, Ksum, Out);
}

// Round 5
// 77.230 us; speedup vs baseline: 1.4169x; 1.4169x over previous
//
#include <hip/hip_runtime.h>

// Causal linear attention (ELU+1), chunked bf16-MFMA, 3 plain launches.
// R13 = revert to R8 (best measured: 77.7/77.9us). Post-mortem ledger:
//  R9  (global B-frags in k_out)        83.7  -- scattered 16-line gathers
//  R10 (bf16 staging via KB/VT dumps)   80.2  -- ~neutral normalized; +1.5us
//                                               traffic saving masked by
//                                               launch/latency overheads
//  R11 (k1 quadrant split + vec scan)   82.6  -- +4MB HBM, no latency win
//  R12 (in-block prefix, no k_scan)    109.4  -- +127MB redundant prefix
//                                               reads at ~HBM speed
// Conclusion: 3-kernel structure with shared k_scan is traffic-optimal
// (~68MB ~= 11us); residual ~20us is launch/drain + short-kernel latency,
// not addressable intra-kernel; spin-barrier fusion unsafe (G16), coop
// launch +30us (R7). This file is byte-identical to the R8 optimum.
//  k1    (NC,B,2): coalesced reads + swizzled LDS transpose -> S_c^T + ksum
//  k_scan: exclusive chunk prefix, prefetch-all-32 (1 latency wait)
//  k_out (NC,B,4): coalesced staging (V^T via LDS swizzle), MFMA GEMMs,
//                  z folded into MFMA (ones-B rowsum + kprev frags).
// Swizzle: elem (l, row) stored at col ((l>>3 + row>>2)&15)*8 + (l&7);
// read frag (row, kq) at ((kq + row>>2)&15)*8  (verified in R7's k_fused).
// Harness floor ~46us (256MB ws poison fill + input restore).

#define EPS 1e-6f

constexpr int Bc = 2;
constexpr int L  = 4096;
constexpr int D  = 128;
constexpr int C  = 128;
constexpr int NC = L / C;   // 32
constexpr int P  = 136;     // LDS row pitch (bf16), rows 16B-aligned

typedef short sh8 __attribute__((ext_vector_type(8)));
typedef float f4  __attribute__((ext_vector_type(4)));

__device__ __forceinline__ float phi(float x) {
    return x > 0.0f ? x + 1.0f : __expf(x);
}
__device__ __forceinline__ unsigned short f2bf(float f) {
    unsigned u = __float_as_uint(f);
    return (unsigned short)((u + 0x7FFFu + ((u >> 16) & 1u)) >> 16);  // RNE
}
__device__ __forceinline__ float bf2f(unsigned short h) {
    return __uint_as_float(((unsigned)h) << 16);
}
__device__ __forceinline__ unsigned packbf(float a, float b) {
    return (unsigned)f2bf(a) | ((unsigned)f2bf(b) << 16);
}
__device__ __forceinline__ sh8 splat1() {
    sh8 s;
#pragma unroll
    for (int j = 0; j < 8; ++j) s[j] = (short)0x3F80;
    return s;
}

// ---------------------------------------------------------------------------
// k1 (NC,B,2), 512 thr: S_c^T[v][i] = sum_l V[l][v] phiK[l][i] + ksum.
// vs = v half.  All global reads coalesced; transposes in LDS via swizzle.
// ---------------------------------------------------------------------------
__global__ __launch_bounds__(512) void k1(
    const float* __restrict__ K, const float* __restrict__ V,
    unsigned short* __restrict__ SB, float* __restrict__ Ksum) {
    const int c = blockIdx.x, b = blockIdx.y, vs = blockIdx.z;
    const int tid = threadIdx.x;
    __shared__ __align__(16) unsigned short sVT[64 * P];   // V^T slice [vr][l]
    __shared__ __align__(16) unsigned short sKT[128 * P];  // phiK^T [i][l]
    const size_t base = ((size_t)b * L + (size_t)c * C) * D;

    // V slice: 128 rows x 64 cols f32 = 2048 float4, coalesced
    for (int k = 0; k < 4; ++k) {
        int fi = tid + 512 * k;
        int l = fi >> 4, c4 = fi & 15;      // c4: 16 float4 per row-slice
        float4 vd = *(const float4*)(V + base + (size_t)l * D + vs * 64 + c4 * 4);
        int blk = (((l >> 3) + c4) & 15) * 8 + (l & 7);   // (c4*4+s)>>2 == c4
        sVT[(c4 * 4 + 0) * P + blk] = f2bf(vd.x);
        sVT[(c4 * 4 + 1) * P + blk] = f2bf(vd.y);
        sVT[(c4 * 4 + 2) * P + blk] = f2bf(vd.z);
        sVT[(c4 * 4 + 3) * P + blk] = f2bf(vd.w);
    }
    // K chunk: 128x128 f32 = 4096 float4, coalesced, phi applied
    for (int k = 0; k < 8; ++k) {
        int fi = tid + 512 * k;
        int l = fi >> 5, i4 = fi & 31;
        float4 kd = *(const float4*)(K + base + (size_t)l * D + i4 * 4);
        int blk = (((l >> 3) + i4) & 15) * 8 + (l & 7);
        sKT[(i4 * 4 + 0) * P + blk] = f2bf(phi(kd.x));
        sKT[(i4 * 4 + 1) * P + blk] = f2bf(phi(kd.y));
        sKT[(i4 * 4 + 2) * P + blk] = f2bf(phi(kd.z));
        sKT[(i4 * 4 + 3) * P + blk] = f2bf(phi(kd.w));
    }
    __syncthreads();

    const int w = tid >> 6, lane = tid & 63;
    const int r = lane & 15, q = lane >> 4;
    const int rbase = (w & 3) * 16;        // v rows within 64
    const int cbase = (w >> 2) * 64;       // i cols: w<4 -> 0, w>=4 -> 64
    const bool doK = ((w & 3) == 0);       // waves 0 (i<64) and 4 (i>=64)
    const sh8 ones = splat1();

    f4 acc[4], kz[4];
#pragma unroll
    for (int f = 0; f < 4; ++f) { acc[f] = {0.f,0.f,0.f,0.f}; kz[f] = {0.f,0.f,0.f,0.f}; }
#pragma unroll
    for (int ks = 0; ks < 4; ++ks) {
        int kq = ks * 4 + q;
        int vr = rbase + r;
        sh8 a = *(const sh8*)(sVT + vr * P + ((kq + (vr >> 2)) & 15) * 8);
#pragma unroll
        for (int f = 0; f < 4; ++f) {
            int ir = cbase + f * 16 + r;
            sh8 bk = *(const sh8*)(sKT + ir * P + ((kq + (ir >> 2)) & 15) * 8);
            acc[f] = __builtin_amdgcn_mfma_f32_16x16x32_bf16(a, bk, acc[f], 0, 0, 0);
            if (doK) kz[f] = __builtin_amdgcn_mfma_f32_16x16x32_bf16(ones, bk, kz[f], 0, 0, 0);
        }
    }
    unsigned short* out = SB + ((size_t)(b * NC + c)) * D * D;
#pragma unroll
    for (int f = 0; f < 4; ++f) {
        int i = cbase + f * 16 + r;
#pragma unroll
        for (int e = 0; e < 4; ++e) {
            int v = vs * 64 + rbase + q * 4 + e;
            out[(size_t)v * D + i] = f2bf(acc[f][e]);
        }
    }
    if (doK && q == 0 && vs == 0) {        // colsum rows identical; row 0
#pragma unroll
        for (int f = 0; f < 4; ++f)
            Ksum[((size_t)(b * NC + c)) * D + cbase + f * 16 + r] = kz[f][0];
    }
}

// ---------------------------------------------------------------------------
// k_scan: exclusive prefix over chunks; prefetch all 32 (independent loads,
// one wait) then prefix+store.
// ---------------------------------------------------------------------------
__global__ __launch_bounds__(256) void k_scan(unsigned short* __restrict__ SB,
                                              float* __restrict__ Ksum) {
    const int SD = D * D;
    int idx = blockIdx.x * 256 + threadIdx.x;
    if (idx < Bc * SD) {
        int b = idx / SD, e = idx % SD;
        size_t off0 = (size_t)b * NC * SD + e;
        unsigned short vals[NC];
#pragma unroll
        for (int c = 0; c < NC; ++c) vals[c] = SB[off0 + (size_t)c * SD];
        float run = 0.0f;
#pragma unroll
        for (int c = 0; c < NC; ++c) {
            SB[off0 + (size_t)c * SD] = f2bf(run);
            run += bf2f(vals[c]);
        }
    } else if (idx < Bc * SD + Bc * D) {
        int rr = idx - Bc * SD;
        int b = rr >> 7, i = rr & 127;
        size_t off0 = (size_t)b * NC * D + i;
        float vals[NC];
#pragma unroll
        for (int c = 0; c < NC; ++c) vals[c] = Ksum[off0 + (size_t)c * D];
        float run = 0.0f;
#pragma unroll
        for (int c = 0; c < NC; ++c) {
            Ksum[off0 + (size_t)c * D] = run;
            run += vals[c];
        }
    }
}

// ---------------------------------------------------------------------------
// k_out (NC,B,4), rows split 4x32, 512 thr (8 waves: rbase=(w&1)*16,
// col quarter cq=w>>1).  All staging coalesced; V^T via LDS swizzle;
// S_prev^T reuses sK after GEMM2.  z fully in MFMA.
// ---------------------------------------------------------------------------
__global__ __launch_bounds__(512) void k_out(
    const float* __restrict__ Q, const float* __restrict__ K,
    const float* __restrict__ V, const unsigned short* __restrict__ SB,
    const float* __restrict__ Ksum, float* __restrict__ Out) {
    const int c = blockIdx.x, b = blockIdx.y, rs = blockIdx.z;
    const int tid = threadIdx.x;
    __shared__ __align__(16) unsigned short sQ[32 * P];    // phiQ rows
    __shared__ __align__(16) unsigned short sK[128 * P];   // phiK rows -> S^T
    __shared__ __align__(16) unsigned short sVT[128 * P];  // V^T swizzled
    __shared__ __align__(16) unsigned short sAm[32 * P];   // masked A
    __shared__ float sZ[32];
    const size_t base  = ((size_t)b * L + (size_t)c * C) * D;
    const size_t tbase = ((size_t)(b * NC + c)) * (size_t)D * D;
    const size_t kb    = ((size_t)(b * NC + c)) * D;

    // phiQ slice: 1024 float4
    for (int k = 0; k < 2; ++k) {
        int fi = tid + 512 * k;
        int row = fi >> 5, c4 = fi & 31;
        float4 qd = *(const float4*)(Q + base + (size_t)(rs * 32 + row) * D + c4 * 4);
        uint2 pq; pq.x = packbf(phi(qd.x), phi(qd.y)); pq.y = packbf(phi(qd.z), phi(qd.w));
        *(uint2*)(sQ + row * P + c4 * 4) = pq;
    }
    // phiK rows: 4096 float4, row-major
    for (int k = 0; k < 8; ++k) {
        int fi = tid + 512 * k;
        int row = fi >> 5, c4 = fi & 31;
        float4 kd = *(const float4*)(K + base + (size_t)row * D + c4 * 4);
        uint2 pk; pk.x = packbf(phi(kd.x), phi(kd.y)); pk.y = packbf(phi(kd.z), phi(kd.w));
        *(uint2*)(sK + row * P + c4 * 4) = pk;
    }
    // V^T: 4096 float4 coalesced, swizzled transpose
    for (int k = 0; k < 8; ++k) {
        int fi = tid + 512 * k;
        int l = fi >> 5, i4 = fi & 31;
        float4 vd = *(const float4*)(V + base + (size_t)l * D + i4 * 4);
        int blk = (((l >> 3) + i4) & 15) * 8 + (l & 7);
        sVT[(i4 * 4 + 0) * P + blk] = f2bf(vd.x);
        sVT[(i4 * 4 + 1) * P + blk] = f2bf(vd.y);
        sVT[(i4 * 4 + 2) * P + blk] = f2bf(vd.z);
        sVT[(i4 * 4 + 3) * P + blk] = f2bf(vd.w);
    }
    __syncthreads();                       // S1

    const int w = tid >> 6, lane = tid & 63;
    const int r = lane & 15, q = lane >> 4;
    const int rbase = (w & 1) * 16;
    const int cq = w >> 1, cbase = cq * 32;
    const bool doZ = (cq == 3);            // rows covered by w=6 (rbase 0), w=7 (16)

    // kprev B-frags for GEMM4 z (r-invariant; L2-hot)
    sh8 bzk[4];
    if (doZ) {
#pragma unroll
        for (int ks = 0; ks < 4; ++ks) {
            float4 f0 = *(const float4*)(Ksum + kb + ks * 32 + q * 8);
            float4 f1 = *(const float4*)(Ksum + kb + ks * 32 + q * 8 + 4);
            sh8 t;
            t[0] = (short)f2bf(f0.x); t[1] = (short)f2bf(f0.y);
            t[2] = (short)f2bf(f0.z); t[3] = (short)f2bf(f0.w);
            t[4] = (short)f2bf(f1.x); t[5] = (short)f2bf(f1.y);
            t[6] = (short)f2bf(f1.z); t[7] = (short)f2bf(f1.w);
            bzk[ks] = t;
        }
    }

    // ---- GEMM2: A = phiQ phiK^T ----
    f4 a2[2];
#pragma unroll
    for (int f = 0; f < 2; ++f) a2[f] = {0.f,0.f,0.f,0.f};
#pragma unroll
    for (int ks = 0; ks < 4; ++ks) {
        sh8 a = *(const sh8*)(sQ + (rbase + r) * P + ks * 32 + q * 8);
#pragma unroll
        for (int f = 0; f < 2; ++f) {
            sh8 bb = *(const sh8*)(sK + (cbase + f * 16 + r) * P + ks * 32 + q * 8);
            a2[f] = __builtin_amdgcn_mfma_f32_16x16x32_bf16(a, bb, a2[f], 0, 0, 0);
        }
    }
#pragma unroll
    for (int f = 0; f < 2; ++f) {          // causal mask -> sAm bf16
        int j = cbase + f * 16 + r;
#pragma unroll
        for (int e = 0; e < 4; ++e) {
            int lr = rbase + q * 4 + e;
            sAm[lr * P + j] = f2bf((j <= rs * 32 + lr) ? a2[f][e] : 0.f);
        }
    }
    __syncthreads();                       // S2: sAm ready, sK reads done

    // restage sK <- S_prev^T (row-major bf16, 2048 uint4; overlaps GEMM3)
    {
        const uint4* sg = (const uint4*)(SB + tbase);
        for (int k = 0; k < 4; ++k) {
            int f2 = tid + 512 * k;
            *(uint4*)(sK + (f2 >> 4) * P + (f2 & 15) * 8) = sg[f2];
        }
    }

    // ---- GEMM3: acc = Am @ V (+ rowsum z via ones-B) ----
    f4 acc[2], zacc = {0.f,0.f,0.f,0.f};
#pragma unroll
    for (int f = 0; f < 2; ++f) acc[f] = {0.f,0.f,0.f,0.f};
    const sh8 ones = splat1();
#pragma unroll
    for (int ks = 0; ks < 4; ++ks) {
        int kq = ks * 4 + q;
        sh8 a = *(const sh8*)(sAm + (rbase + r) * P + ks * 32 + q * 8);
#pragma unroll
        for (int f = 0; f < 2; ++f) {
            int vr = cbase + f * 16 + r;
            sh8 bv = *(const sh8*)(sVT + vr * P + ((kq + (vr >> 2)) & 15) * 8);
            acc[f] = __builtin_amdgcn_mfma_f32_16x16x32_bf16(a, bv, acc[f], 0, 0, 0);
        }
        if (doZ) zacc = __builtin_amdgcn_mfma_f32_16x16x32_bf16(a, ones, zacc, 0, 0, 0);
    }
    __syncthreads();                       // S3: sK = S^T ready

    // ---- GEMM4: acc += phiQ @ S_prev (+ kprev z) ----
#pragma unroll
    for (int ks = 0; ks < 4; ++ks) {
        sh8 a = *(const sh8*)(sQ + (rbase + r) * P + ks * 32 + q * 8);
#pragma unroll
        for (int f = 0; f < 2; ++f) {
            sh8 bs = *(const sh8*)(sK + (cbase + f * 16 + r) * P + ks * 32 + q * 8);
            acc[f] = __builtin_amdgcn_mfma_f32_16x16x32_bf16(a, bs, acc[f], 0, 0, 0);
        }
        if (doZ) zacc = __builtin_amdgcn_mfma_f32_16x16x32_bf16(a, bzk[ks], zacc, 0, 0, 0);
    }
    if (doZ && r == 0) {
#pragma unroll
        for (int e = 0; e < 4; ++e) sZ[rbase + q * 4 + e] = zacc[e] + EPS;
    }
    __syncthreads();                       // S4: sZ ready

    // ---- normalize + store ----
#pragma unroll
    for (int f = 0; f < 2; ++f) {
        int v = cbase + f * 16 + r;
#pragma unroll
        for (int e = 0; e < 4; ++e) {
            int lr = rbase + q * 4 + e;
            Out[base + (size_t)(rs * 32 + lr) * D + v] = acc[f][e] / sZ[lr];
        }
    }
}

extern "C" void kernel_launch(void* const* d_in, const int* in_sizes, int n_in,
                              void* d_out, int out_size, void* d_ws, size_t ws_size,
                              hipStream_t stream) {
    const float* Q = (const float*)d_in[0];
    const float* K = (const float*)d_in[1];
    const float* V = (const float*)d_in[2];
    float* Out = (float*)d_out;
    unsigned short* SBw = (unsigned short*)d_ws;                        // 2 MB
    float* Ksum = (float*)((char*)d_ws + (size_t)Bc * NC * D * D * 2);  // 32 KB

    k1<<<dim3(NC, Bc, 2), 512, 0, stream>>>(K, V, SBw, Ksum);
    int total = Bc * D * D + Bc * D;
    k_scan<<<dim3((total + 255) / 256), 256, 0, stream>>>(SBw, Ksum);
    k_out<<<dim3(NC, Bc, 4), 512, 0, stream>>>(Q, K, V, SBw, Ksum, Out);
}